// Round 1
// baseline (1165.697 us; speedup 1.0000x reference)
//
#include <hip/hip_runtime.h>

#define D_FEAT 64

// One wave (64 lanes) per nonzero edge e; lane d handles feature dim d.
// Gather read feat[c*64+d] is one coalesced 256B access per wave.
// rows/cols/vals reads are wave-uniform (same addr all lanes -> broadcast).
__global__ __launch_bounds__(256) void BoundaryOperator_scatter_kernel(
    const float* __restrict__ feat,
    const float* __restrict__ vals,
    const int*   __restrict__ rows,
    const int*   __restrict__ cols,
    float*       __restrict__ out,
    long long    nnz)
{
    long long tid = (long long)blockIdx.x * blockDim.x + threadIdx.x;
    long long e   = tid >> 6;          // one edge per wave
    int       d   = (int)(tid & 63);   // lane = feature dim
    if (e >= nnz) return;

    int   r = rows[e];
    int   c = cols[e];
    float v = vals[e];

    float f = feat[(long long)c * D_FEAT + d];
    atomicAdd(out + (long long)r * D_FEAT + d, v * f);
}

extern "C" void kernel_launch(void* const* d_in, const int* in_sizes, int n_in,
                              void* d_out, int out_size, void* d_ws, size_t ws_size,
                              hipStream_t stream) {
    const float* feat = (const float*)d_in[0];  // [NUM_E, 64] fp32
    const float* vals = (const float*)d_in[1];  // [NNZ] fp32 (+/-1)
    const int*   rows = (const int*)d_in[2];    // [NNZ] int32
    const int*   cols = (const int*)d_in[3];    // [NNZ] int32
    float*       out  = (float*)d_out;          // [NUM_V, 64] fp32

    long long nnz = in_sizes[1];

    // d_out is poisoned with 0xAA before every launch -> zero it first.
    hipMemsetAsync(d_out, 0, (size_t)out_size * sizeof(float), stream);

    long long total  = nnz * D_FEAT;
    int       block  = 256;
    long long nblock = (total + block - 1) / block;
    BoundaryOperator_scatter_kernel<<<(dim3)((unsigned)nblock), block, 0, stream>>>(
        feat, vals, rows, cols, out, nnz);
}

// Round 2
// 979.883 us; speedup vs baseline: 1.1896x; 1.1896x over previous
//
#include <hip/hip_runtime.h>

#define D_FEAT 64
#define SCAN_BLOCK 256
#define SCAN_ITEMS 16
#define SCAN_CHUNK (SCAN_BLOCK * SCAN_ITEMS)   // 4096 elements per scan block
#define SCANB_THREADS 1024                     // supports up to 1024 scan blocks (~4.2M rows)

typedef unsigned int u32;

// ---------------- Phase 1: per-row counts (atomics on small L2-resident array) --------
__global__ __launch_bounds__(256) void count_kernel(const int* __restrict__ rows,
                                                    u32* __restrict__ cnt, int nnz) {
    int e = blockIdx.x * blockDim.x + threadIdx.x;
    if (e < nnz) atomicAdd(&cnt[rows[e]], 1u);
}

// ---------------- Phase 2: exclusive scan of cnt -> off (3 kernels) ------------------
__global__ __launch_bounds__(SCAN_BLOCK) void scanA_kernel(const u32* __restrict__ cnt,
                                                           u32* __restrict__ bsums, int n) {
    int t = threadIdx.x, b = blockIdx.x;
    int i0 = b * SCAN_CHUNK + t * SCAN_ITEMS;
    u32 s = 0;
#pragma unroll
    for (int k = 0; k < SCAN_ITEMS; ++k) {
        int i = i0 + k;
        if (i < n) s += cnt[i];
    }
    __shared__ u32 red[SCAN_BLOCK];
    red[t] = s;
    __syncthreads();
    for (int d = SCAN_BLOCK / 2; d > 0; d >>= 1) {
        if (t < d) red[t] += red[t + d];
        __syncthreads();
    }
    if (t == 0) bsums[b] = red[0];
}

__global__ __launch_bounds__(SCANB_THREADS) void scanB_kernel(u32* __restrict__ bsums, int nb,
                                                              u32* __restrict__ off, int numV,
                                                              u32 nnz) {
    int t = threadIdx.x;
    __shared__ u32 tmp[SCANB_THREADS];
    u32 v = (t < nb) ? bsums[t] : 0u;
    tmp[t] = v;
    __syncthreads();
    for (int d = 1; d < SCANB_THREADS; d <<= 1) {
        u32 x = (t >= d) ? tmp[t - d] : 0u;
        __syncthreads();
        tmp[t] += x;
        __syncthreads();
    }
    if (t < nb) bsums[t] = tmp[t] - v;   // exclusive
    if (t == 0) off[numV] = nnz;
}

__global__ __launch_bounds__(SCAN_BLOCK) void scanC_kernel(const u32* __restrict__ cnt,
                                                           const u32* __restrict__ bsums,
                                                           u32* __restrict__ off,
                                                           u32* __restrict__ cursor, int n) {
    int t = threadIdx.x, b = blockIdx.x;
    int i0 = b * SCAN_CHUNK + t * SCAN_ITEMS;
    u32 s = 0;
#pragma unroll
    for (int k = 0; k < SCAN_ITEMS; ++k) {
        int i = i0 + k;
        if (i < n) s += cnt[i];
    }
    __shared__ u32 tmp[SCAN_BLOCK];
    tmp[t] = s;
    __syncthreads();
    for (int d = 1; d < SCAN_BLOCK; d <<= 1) {
        u32 x = (t >= d) ? tmp[t - d] : 0u;
        __syncthreads();
        tmp[t] += x;
        __syncthreads();
    }
    u32 run = bsums[b] + (tmp[t] - s);   // block base + exclusive within block
    for (int k = 0; k < SCAN_ITEMS; ++k) {
        int i = i0 + k;
        if (i < n) {
            off[i] = run;
            cursor[i] = run;
            run += cnt[i];
        }
    }
}

// ---------------- Phase 3: scatter edges into CSR order, sign packed in bit 31 -------
// Values are guaranteed +/-1 by the problem setup, so only the sign is stored.
__global__ __launch_bounds__(256) void scatter_kernel(const int* __restrict__ rows,
                                                      const int* __restrict__ cols,
                                                      const float* __restrict__ vals,
                                                      u32* __restrict__ cursor,
                                                      u32* __restrict__ packed, int nnz) {
    int e = blockIdx.x * blockDim.x + threadIdx.x;
    if (e >= nnz) return;
    int r = rows[e];
    u32 pos = atomicAdd(&cursor[r], 1u);
    u32 entry = (u32)cols[e] | (vals[e] < 0.f ? 0x80000000u : 0u);
    packed[pos] = entry;
}

// ---------------- Phase 4: one wave per row, gather + reduce, single store -----------
__global__ __launch_bounds__(256) void gather_kernel(const float* __restrict__ feat,
                                                     const u32* __restrict__ off,
                                                     const u32* __restrict__ packed,
                                                     float* __restrict__ out, int numV) {
    long long tid = (long long)blockIdx.x * blockDim.x + threadIdx.x;
    long long wid = tid >> 6;          // one row per wave
    int lane = (int)(tid & 63);        // lane = feature dim
    if (wid >= numV) return;

    u32 s = off[wid];
    u32 e = off[wid + 1];
    float acc = 0.f;

    for (u32 base = s; base < e; base += 64) {
        int cnt = (int)min(64u, e - base);
        u32 ent = (lane < cnt) ? packed[base + lane] : 0u;
        for (int j0 = 0; j0 < cnt; j0 += 4) {
            float f[4], sg[4];
#pragma unroll
            for (int k = 0; k < 4; ++k) {
                int j = j0 + k;
                u32 ej = __shfl(ent, j);
                long long c = (long long)(ej & 0x7fffffffu);
                sg[k] = (ej >> 31) ? -1.f : 1.f;
                f[k] = (j < cnt) ? feat[c * D_FEAT + lane] : 0.f;  // 4 loads in flight
            }
#pragma unroll
            for (int k = 0; k < 4; ++k) acc = fmaf(sg[k], f[k], acc);
        }
    }
    out[wid * D_FEAT + lane] = acc;    // every row written once (degree-0 rows -> 0)
}

// ---------------- Fallback: round-1 atomic scatter (if ws too small) -----------------
__global__ __launch_bounds__(256) void atomic_fallback_kernel(
    const float* __restrict__ feat, const float* __restrict__ vals,
    const int* __restrict__ rows, const int* __restrict__ cols,
    float* __restrict__ out, long long nnz) {
    long long tid = (long long)blockIdx.x * blockDim.x + threadIdx.x;
    long long e = tid >> 6;
    int d = (int)(tid & 63);
    if (e >= nnz) return;
    float f = feat[(long long)cols[e] * D_FEAT + d];
    atomicAdd(out + (long long)rows[e] * D_FEAT + d, vals[e] * f);
}

extern "C" void kernel_launch(void* const* d_in, const int* in_sizes, int n_in,
                              void* d_out, int out_size, void* d_ws, size_t ws_size,
                              hipStream_t stream) {
    const float* feat = (const float*)d_in[0];  // [NUM_E, 64] fp32
    const float* vals = (const float*)d_in[1];  // [NNZ] fp32 (+/-1)
    const int*   rows = (const int*)d_in[2];    // [NNZ] int32
    const int*   cols = (const int*)d_in[3];    // [NNZ] int32
    float*       out  = (float*)d_out;          // [NUM_V, 64] fp32

    int nnz  = in_sizes[1];
    int numV = out_size / D_FEAT;

    int nScanBlocks = (numV + SCAN_CHUNK - 1) / SCAN_CHUNK;

    // workspace layout (all u32)
    // [off: numV+1][cursor: numV][cnt: numV][bsums: SCANB_THREADS][packed: nnz]
    size_t need = ((size_t)(numV + 1) + numV + numV + SCANB_THREADS + nnz) * sizeof(u32);

    if (ws_size < need || nScanBlocks > SCANB_THREADS) {
        // fallback: atomic scatter (round-1 path)
        hipMemsetAsync(d_out, 0, (size_t)out_size * sizeof(float), stream);
        long long total = (long long)nnz * D_FEAT;
        long long nblk = (total + 255) / 256;
        atomic_fallback_kernel<<<(dim3)((unsigned)nblk), 256, 0, stream>>>(
            feat, vals, rows, cols, out, nnz);
        return;
    }

    u32* ws     = (u32*)d_ws;
    u32* off    = ws;
    u32* cursor = off + (numV + 1);
    u32* cnt    = cursor + numV;
    u32* bsums  = cnt + numV;
    u32* packed = bsums + SCANB_THREADS;

    hipMemsetAsync(cnt, 0, (size_t)numV * sizeof(u32), stream);

    int nb256 = (nnz + 255) / 256;
    count_kernel<<<nb256, 256, 0, stream>>>(rows, cnt, nnz);
    scanA_kernel<<<nScanBlocks, SCAN_BLOCK, 0, stream>>>(cnt, bsums, numV);
    scanB_kernel<<<1, SCANB_THREADS, 0, stream>>>(bsums, nScanBlocks, off, numV, (u32)nnz);
    scanC_kernel<<<nScanBlocks, SCAN_BLOCK, 0, stream>>>(cnt, bsums, off, cursor, numV);
    scatter_kernel<<<nb256, 256, 0, stream>>>(rows, cols, vals, cursor, packed, nnz);

    long long gthreads = (long long)numV * 64;
    long long gblocks  = (gthreads + 255) / 256;
    gather_kernel<<<(dim3)((unsigned)gblocks), 256, 0, stream>>>(feat, off, packed, out, numV);
}